// Round 1
// baseline (694.174 us; speedup 1.0000x reference)
//
#include <hip/hip_runtime.h>

#define N_NODES 50000
#define E_EDGES 800000
#define IN_F    128
#define H_F     64
#define STD_EPS 1e-5f
#define BN_EPS  1e-5f

#define HIST_BLK 3125   // E_EDGES / 256 exactly
#define EMB_BLK  768
#define SCAN_BLK 49
#define TRANS_BLK 448   // 114688 / 256

typedef __attribute__((ext_vector_type(8))) short bf16x8;
typedef __attribute__((ext_vector_type(4))) float f32x4;

// float -> bf16 bits (round-to-nearest-even), in low 16 bits
__device__ __forceinline__ unsigned bf16_rne(float f) {
  unsigned u = __float_as_uint(f);
  return (u + 0x7fffu + ((u >> 16) & 1u)) >> 16;
}
// split (x,y) into packed bf16x2 hi and bf16x2 lo (residual)
__device__ __forceinline__ void bf16_split2(float x, float y, unsigned& hi, unsigned& lo) {
  unsigned hx = bf16_rne(x), hy = bf16_rne(y);
  float rx = x - __uint_as_float(hx << 16);
  float ry = y - __uint_as_float(hy << 16);
  hi = hx | (hy << 16);
  lo = bf16_rne(rx) | (bf16_rne(ry) << 16);
}

#define MFMA(acc, a, b) acc = __builtin_amdgcn_mfma_f32_16x16x32_bf16(a, b, acc, 0, 0, 0)

// ------------------------------------------- fused degree hist + embed GEMM
__global__ __launch_bounds__(256) void k_hist_embed(const int* __restrict__ dst,
                                                    int* __restrict__ deg,
                                                    const float* __restrict__ x,
                                                    const float* __restrict__ W,
                                                    const float* __restrict__ bias,
                                                    float* __restrict__ h) {
  __shared__ float sW[IN_F * 64];    // 32 KB
  __shared__ float sx[IN_F * 36];    // x_T[k][32+pad4] 18 KB
  if (blockIdx.x < HIST_BLK) {
    int e = blockIdx.x * 256 + threadIdx.x;
    atomicAdd(&deg[dst[e]], 1);      // grid sized so e < E_EDGES always
    return;
  }
  for (int i = threadIdx.x; i < IN_F * 64; i += 256) sW[i] = W[i];
  int f = threadIdx.x & 63, ng = threadIdx.x >> 6;
  float bj = bias[f];
  const int NGRP = (N_NODES + 31) / 32;   // 1563
  for (int grp = blockIdx.x - HIST_BLK; grp < NGRP; grp += EMB_BLK) {
    int n0 = grp * 32;
    __syncthreads();
    for (int idx = threadIdx.x; idx < 32 * IN_F; idx += 256) {
      int nl = idx >> 7, k = idx & 127;
      int n = n0 + nl;
      sx[k * 36 + nl] = (n < N_NODES) ? x[(size_t)n * IN_F + k] : 0.f;
    }
    __syncthreads();
    float a[8] = {bj, bj, bj, bj, bj, bj, bj, bj};
    const float* xp = &sx[ng * 8];
#pragma unroll 4
    for (int k = 0; k < IN_F; k++) {
      float4 h0 = *(const float4*)&xp[k * 36];
      float4 h1 = *(const float4*)&xp[k * 36 + 4];
      float w = sW[k * 64 + f];
      a[0] = fmaf(h0.x, w, a[0]); a[1] = fmaf(h0.y, w, a[1]);
      a[2] = fmaf(h0.z, w, a[2]); a[3] = fmaf(h0.w, w, a[3]);
      a[4] = fmaf(h1.x, w, a[4]); a[5] = fmaf(h1.y, w, a[5]);
      a[6] = fmaf(h1.z, w, a[6]); a[7] = fmaf(h1.w, w, a[7]);
    }
#pragma unroll
    for (int j = 0; j < 8; j++) {
      int n = n0 + ng * 8 + j;
      if (n < N_NODES) h[(size_t)n * 64 + f] = a[j];
    }
  }
}

// --------------------- fused scan phase-1 (+ sum log(deg+1)) and transpose
// Weight prep now emits bf16 hi/lo split, transposed to [layer][t][col][f=832]
// (k-contiguous per output column -> MFMA B-fragment layout).
__global__ __launch_bounds__(256) void k_scanpart_trans(const int* __restrict__ deg,
                                                        int* __restrict__ partials,
                                                        float* __restrict__ scalars,
                                                        const float* __restrict__ pW1,
                                                        const float* __restrict__ pW2,
                                                        const float* __restrict__ lW1,
                                                        const float* __restrict__ lW2,
                                                        unsigned short* __restrict__ WBhi,
                                                        unsigned short* __restrict__ WBlo,
                                                        float* __restrict__ lWT) {
  __shared__ int red[256];
  __shared__ float redf[256];
  if (blockIdx.x < SCAN_BLK) {
    int base = blockIdx.x * 1024;
    int s = 0; float ls = 0.f;
    for (int j = threadIdx.x; j < 1024; j += 256) {
      int i = base + j;
      if (i < N_NODES) { int d = deg[i]; s += d; ls += logf((float)d + 1.0f); }
    }
    red[threadIdx.x] = s; redf[threadIdx.x] = ls; __syncthreads();
    for (int st = 128; st > 0; st >>= 1) {
      if (threadIdx.x < st) {
        red[threadIdx.x] += red[threadIdx.x + st];
        redf[threadIdx.x] += redf[threadIdx.x + st];
      }
      __syncthreads();
    }
    if (threadIdx.x == 0) {
      partials[blockIdx.x] = red[0];
      atomicAdd(&scalars[0], redf[0]);
    }
    return;
  }
  int idx = (blockIdx.x - SCAN_BLK) * 256 + threadIdx.x;
  if (idx < 106496) {
    // idx = ((layer*2 + t)*32 + col)*832 + f
    int f = idx % 832;
    int rest = idx / 832;            // 0..127
    int col = rest & 31, tt = rest >> 5;   // tt = layer*2 + t
    const float* srcp = (tt >= 2) ? pW2 : pW1;
    float v = srcp[((size_t)(tt & 1) * 832 + f) * 32 + col];
    unsigned hb = bf16_rne(v);
    float rsd = v - __uint_as_float(hb << 16);
    WBhi[idx] = (unsigned short)hb;
    WBlo[idx] = (unsigned short)bf16_rne(rsd);
  } else if (idx < 114688) {
    int jj = idx - 106496;
    int layer = jj / 4096, r2 = jj % 4096;
    int c4 = r2 / 256, r3 = r2 % 256;
    int col = r3 / 4, j = r3 % 4;
    const float* srcl = layer ? lW2 : lW1;
    lWT[jj] = srcl[(c4 * 4 + j) * 64 + col];
  }
}

// ----------------------- scan final (self-computed prefix, no mid kernel)
__global__ __launch_bounds__(256) void k_scan_final(const int* __restrict__ deg,
                                                    const int* __restrict__ partials,
                                                    int* __restrict__ row_ptr,
                                                    int* __restrict__ cursor,
                                                    float* __restrict__ scalars) {
  __shared__ int ts[256];
  __shared__ int sbase;
  if (threadIdx.x == 0) {
    int pre = 0;
    for (int b = 0; b < (int)blockIdx.x; b++) pre += partials[b];
    sbase = pre;
    if (blockIdx.x == 0) {
      scalars[1] = scalars[0] / (float)N_NODES;   // avg_log
      row_ptr[N_NODES] = E_EDGES;
    }
  }
  int base = blockIdx.x * 1024 + threadIdx.x * 4;
  int d[4]; int s = 0;
#pragma unroll
  for (int j = 0; j < 4; j++) {
    int i = base + j;
    d[j] = (i < N_NODES) ? deg[i] : 0;
    s += d[j];
  }
  ts[threadIdx.x] = s; __syncthreads();
  for (int off = 1; off < 256; off <<= 1) {
    int t = (threadIdx.x >= off) ? ts[threadIdx.x - off] : 0;
    __syncthreads();
    ts[threadIdx.x] += t;
    __syncthreads();
  }
  int excl = (threadIdx.x > 0) ? ts[threadIdx.x - 1] : 0;
  int run = sbase + excl;
#pragma unroll
  for (int j = 0; j < 4; j++) {
    int i = base + j;
    if (i < N_NODES) { row_ptr[i] = run; cursor[i] = run; run += d[j]; }
  }
}

// ------------------------------------------------------------------- scatter
__global__ __launch_bounds__(256) void k_scatter(const int* __restrict__ src,
                                                 const int* __restrict__ dst,
                                                 int* __restrict__ cursor,
                                                 int* __restrict__ csr_src) {
  int e = blockIdx.x * 256 + threadIdx.x;
  if (e < E_EDGES) {
    int d = dst[e];
    int p = atomicAdd(&cursor[d], 1);
    csr_src[p] = src[e];
  }
}

// ------------------------------------------------------------------ pre A/B
template <bool BN>
__global__ __launch_bounds__(256) void k_preab(const float* __restrict__ hin,
                                               const float* __restrict__ preW,
                                               const float* __restrict__ preb,
                                               const float* __restrict__ bnsum,
                                               const float* __restrict__ bnsumsq,
                                               const float* __restrict__ gamma,
                                               const float* __restrict__ beta,
                                               float* __restrict__ h2out,
                                               float* __restrict__ hA,
                                               float* __restrict__ hB) {
  __shared__ float sWp[64 * 128];   // 32 KB packed [k][f][{A,B}]
  __shared__ float sh[64 * 68];     // h_T[k][64+pad4]  17408 B
  __shared__ float sbn[128];        // scale[64], shift[64]
  int t = blockIdx.x & 1;
  const float* Wsrc = preW + (size_t)t * 128 * 64;
  for (int i = threadIdx.x; i < 64 * 64; i += 256) {
    int k = i >> 6, f = i & 63;
    float wa = Wsrc[k * 64 + f];
    float wb = Wsrc[(64 + k) * 64 + f];
    *(float2*)&sWp[k * 128 + f * 2] = make_float2(wa, wb);
  }
  if (BN && threadIdx.x < 64) {
    int c = threadIdx.x;
    float mu = bnsum[c] * (1.f / N_NODES);
    float var = bnsumsq[c] * (1.f / N_NODES) - mu * mu;
    float sc = gamma[c] / sqrtf(var + BN_EPS);
    sbn[c] = sc;
    sbn[64 + c] = fmaf(-mu, sc, beta[c]);
  }
  int f = threadIdx.x & 63, ng = threadIdx.x >> 6;   // ng 0..3 -> 16 nodes each
  float pb = preb[t * 64 + f];
  int nblk2 = gridDim.x >> 1;
  const int NGRP = (N_NODES + 63) / 64;   // 782
  for (int grp = blockIdx.x >> 1; grp < NGRP; grp += nblk2) {
    int n0 = grp * 64;
    __syncthreads();
    for (int idx = threadIdx.x; idx < 64 * 64; idx += 256) {
      int nl = idx >> 6, k = idx & 63;
      int n = n0 + nl;
      float v = 0.f;
      if (n < N_NODES) {
        v = hin[(size_t)n * 64 + k];
        if (BN) {
          v = fmaxf(fmaf(v, sbn[k], sbn[64 + k]), 0.f);
          if (t == 0) h2out[(size_t)n * 64 + k] = v;
        }
      }
      sh[k * 68 + nl] = v;
    }
    __syncthreads();
    float a[16], b[16];
#pragma unroll
    for (int j = 0; j < 16; j++) { a[j] = pb; b[j] = 0.f; }
    const float* hp = &sh[ng * 16];
    const float* wp = &sWp[f * 2];
#pragma unroll 2
    for (int k = 0; k < 64; k++) {
      float4 h0 = *(const float4*)&hp[k * 68];
      float4 h1 = *(const float4*)&hp[k * 68 + 4];
      float4 h2 = *(const float4*)&hp[k * 68 + 8];
      float4 h3 = *(const float4*)&hp[k * 68 + 12];
      float2 w2 = *(const float2*)&wp[k * 128];
      a[0]  = fmaf(h0.x, w2.x, a[0]);  b[0]  = fmaf(h0.x, w2.y, b[0]);
      a[1]  = fmaf(h0.y, w2.x, a[1]);  b[1]  = fmaf(h0.y, w2.y, b[1]);
      a[2]  = fmaf(h0.z, w2.x, a[2]);  b[2]  = fmaf(h0.z, w2.y, b[2]);
      a[3]  = fmaf(h0.w, w2.x, a[3]);  b[3]  = fmaf(h0.w, w2.y, b[3]);
      a[4]  = fmaf(h1.x, w2.x, a[4]);  b[4]  = fmaf(h1.x, w2.y, b[4]);
      a[5]  = fmaf(h1.y, w2.x, a[5]);  b[5]  = fmaf(h1.y, w2.y, b[5]);
      a[6]  = fmaf(h1.z, w2.x, a[6]);  b[6]  = fmaf(h1.z, w2.y, b[6]);
      a[7]  = fmaf(h1.w, w2.x, a[7]);  b[7]  = fmaf(h1.w, w2.y, b[7]);
      a[8]  = fmaf(h2.x, w2.x, a[8]);  b[8]  = fmaf(h2.x, w2.y, b[8]);
      a[9]  = fmaf(h2.y, w2.x, a[9]);  b[9]  = fmaf(h2.y, w2.y, b[9]);
      a[10] = fmaf(h2.z, w2.x, a[10]); b[10] = fmaf(h2.z, w2.y, b[10]);
      a[11] = fmaf(h2.w, w2.x, a[11]); b[11] = fmaf(h2.w, w2.y, b[11]);
      a[12] = fmaf(h3.x, w2.x, a[12]); b[12] = fmaf(h3.x, w2.y, b[12]);
      a[13] = fmaf(h3.y, w2.x, a[13]); b[13] = fmaf(h3.y, w2.y, b[13]);
      a[14] = fmaf(h3.z, w2.x, a[14]); b[14] = fmaf(h3.z, w2.y, b[14]);
      a[15] = fmaf(h3.w, w2.x, a[15]); b[15] = fmaf(h3.w, w2.y, b[15]);
    }
    int tf = t * 64 + f;
#pragma unroll
    for (int j = 0; j < 16; j++) {
      int n = n0 + ng * 16 + j;
      if (n < N_NODES) {
        hA[(size_t)n * 128 + tf] = a[j];
        hB[(size_t)n * 128 + tf] = b[j];
      }
    }
  }
}

// --------------------------------------------------- fused conv main kernel
// 8 nodes/block. Aggregation unchanged; post-matmul moved to MFMA via
// 3-product bf16 hi/lo split-precision emulation (error ~1e-4 rel, vs 832
// scalar FMAs/col on the VALU). A staged in LDS as bf16 hi/lo rows
// [t][node][336] (336 = 320 feats + 16 pad -> 672B row stride, ~2-way banks).
// M=16 MFMA tile carries nodes 0-7 twice (rows 8-15 duplicates, discarded).
__global__ __launch_bounds__(256, 6) void k_conv(const float* __restrict__ hA,
                                                 const float* __restrict__ hB,
                                                 const float* __restrict__ hskip,
                                                 const int* __restrict__ row_ptr,
                                                 const int* __restrict__ csr_src,
                                                 const unsigned short* __restrict__ WBhi,
                                                 const unsigned short* __restrict__ WBlo,
                                                 const float* __restrict__ postb,
                                                 const float* __restrict__ linWT,
                                                 const float* __restrict__ linb,
                                                 const float* __restrict__ scalars,
                                                 float* __restrict__ out) {
  __shared__ unsigned sAhi[2688];   // [t][node8][168 u32] = 10752 B
  __shared__ unsigned sAlo[2688];   // 10752 B  (total 21568 B -> 7 blk/CU)
  __shared__ float sAB[16];         // sA[0..7], sB[8..15]
  int w = threadIdx.x >> 6, lane = threadIdx.x & 63;
  int n0 = blockIdx.x * 8;
  int t = lane >> 5, fb2 = (lane & 31) * 2;
  int off = t * 64 + fb2;
  float avg = scalars[1];

  // ---- phase A: aggregation, 2 nodes per wave, 4 loads in flight
#pragma unroll 1
  for (int k = 0; k < 2; k++) {
    int nl = w * 2 + k;
    int n = n0 + nl;
    float2 a = *(const float2*)&hA[(size_t)n * 128 + off];
    int rp0 = __builtin_amdgcn_readfirstlane(row_ptr[n]);
    int rp1 = __builtin_amdgcn_readfirstlane(row_ptr[n + 1]);
    float sx0=0,sy0=0,qx0=0,qy0=0, sx1=0,sy1=0,qx1=0,qy1=0;
    float mnx0=INFINITY,mny0=INFINITY,mxx0=-INFINITY,mxy0=-INFINITY;
    float mnx1=INFINITY,mny1=INFINITY,mxx1=-INFINITY,mxy1=-INFINITY;
    int i = rp0;
    int end4 = rp0 + ((rp1 - rp0) & ~3);
    if (i < end4) {
      int s0 = csr_src[i], s1 = csr_src[i+1], s2 = csr_src[i+2], s3 = csr_src[i+3];
      while (true) {
        float2 v0 = *(const float2*)&hB[(size_t)s0 * 128 + off];
        float2 v1 = *(const float2*)&hB[(size_t)s1 * 128 + off];
        float2 v2 = *(const float2*)&hB[(size_t)s2 * 128 + off];
        float2 v3 = *(const float2*)&hB[(size_t)s3 * 128 + off];
        i += 4;
        bool more = (i < end4);
        if (more) { s0 = csr_src[i]; s1 = csr_src[i+1]; s2 = csr_src[i+2]; s3 = csr_src[i+3]; }
        float e0x = v0.x + a.x, e0y = v0.y + a.y;
        float e1x = v1.x + a.x, e1y = v1.y + a.y;
        float e2x = v2.x + a.x, e2y = v2.y + a.y;
        float e3x = v3.x + a.x, e3y = v3.y + a.y;
        sx0 += e0x; qx0 = fmaf(e0x,e0x,qx0); mnx0 = fminf(mnx0,e0x); mxx0 = fmaxf(mxx0,e0x);
        sy0 += e0y; qy0 = fmaf(e0y,e0y,qy0); mny0 = fminf(mny0,e0y); mxy0 = fmaxf(mxy0,e0y);
        sx1 += e1x; qx1 = fmaf(e1x,e1x,qx1); mnx1 = fminf(mnx1,e1x); mxx1 = fmaxf(mxx1,e1x);
        sy1 += e1y; qy1 = fmaf(e1y,e1y,qy1); mny1 = fminf(mny1,e1y); mxy1 = fmaxf(mxy1,e1y);
        sx0 += e2x; qx0 = fmaf(e2x,e2x,qx0); mnx0 = fminf(mnx0,e2x); mxx0 = fmaxf(mxx0,e2x);
        sy0 += e2y; qy0 = fmaf(e2y,e2y,qy0); mny0 = fminf(mny0,e2y); mxy0 = fmaxf(mxy0,e2y);
        sx1 += e3x; qx1 = fmaf(e3x,e3x,qx1); mnx1 = fminf(mnx1,e3x); mxx1 = fmaxf(mxx1,e3x);
        sy1 += e3y; qy1 = fmaf(e3y,e3y,qy1); mny1 = fminf(mny1,e3y); mxy1 = fmaxf(mxy1,e3y);
        if (!more) break;
      }
    }
    {   // masked tail: 0..3 edges, all loads issued together
      int r = rp1 - i;
      if (r > 0) {
        int e1i = (r > 1) ? i + 1 : i;
        int e2i = (r > 2) ? i + 2 : i;
        int t0 = csr_src[i], t1 = csr_src[e1i], t2 = csr_src[e2i];
        float2 u0 = *(const float2*)&hB[(size_t)t0 * 128 + off];
        float2 u1 = *(const float2*)&hB[(size_t)t1 * 128 + off];
        float2 u2 = *(const float2*)&hB[(size_t)t2 * 128 + off];
        float ex = u0.x + a.x, ey = u0.y + a.y;
        sx0 += ex; qx0 = fmaf(ex,ex,qx0); mnx0 = fminf(mnx0,ex); mxx0 = fmaxf(mxx0,ex);
        sy0 += ey; qy0 = fmaf(ey,ey,qy0); mny0 = fminf(mny0,ey); mxy0 = fmaxf(mxy0,ey);
        if (r > 1) {
          ex = u1.x + a.x; ey = u1.y + a.y;
          sx1 += ex; qx1 = fmaf(ex,ex,qx1); mnx1 = fminf(mnx1,ex); mxx1 = fmaxf(mxx1,ex);
          sy1 += ey; qy1 = fmaf(ey,ey,qy1); mny1 = fminf(mny1,ey); mxy1 = fmaxf(mxy1,ey);
        }
        if (r > 2) {
          ex = u2.x + a.x; ey = u2.y + a.y;
          sx0 += ex; qx0 = fmaf(ex,ex,qx0); mnx0 = fminf(mnx0,ex); mxx0 = fmaxf(mxx0,ex);
          sy0 += ey; qy0 = fmaf(ey,ey,qy0); mny0 = fminf(mny0,ey); mxy0 = fmaxf(mxy0,ey);
        }
      }
    }
    int dg = rp1 - rp0;
    float cnt = (float)(dg > 0 ? dg : 1);
    float inv = 1.0f / cnt;
    float meanx = (sx0 + sx1) * inv, meany = (sy0 + sy1) * inv;
    float qx = qx0 + qx1, qy = qy0 + qy1;
    float sdx = sqrtf(fmaxf(qx * inv - meanx * meanx, 0.f) + STD_EPS);
    float sdy = sqrtf(fmaxf(qy * inv - meany * meany, 0.f) + STD_EPS);
    float mnx = fminf(mnx0, mnx1), mny = fminf(mny0, mny1);
    float mxx = fmaxf(mxx0, mxx1), mxy = fmaxf(mxy0, mxy1);
    if (dg == 0) { mnx = 0; mny = 0; mxx = 0; mxy = 0; }
    float ldv = logf(cnt + 1.f);
    float2 hsv = *(const float2*)&hskip[(size_t)n * 64 + fb2];
    // write 5 slices as bf16 hi/lo into A rows (k-contiguous, 672B stride)
    unsigned* ahp = &sAhi[(t * 8 + nl) * 168 + (fb2 >> 1)];
    unsigned* alp = &sAlo[(t * 8 + nl) * 168 + (fb2 >> 1)];
    unsigned hi, lo;
    bf16_split2(hsv.x, hsv.y, hi, lo);   ahp[0]   = hi; alp[0]   = lo;
    bf16_split2(meanx, meany, hi, lo);   ahp[32]  = hi; alp[32]  = lo;
    bf16_split2(mnx, mny, hi, lo);       ahp[64]  = hi; alp[64]  = lo;
    bf16_split2(mxx, mxy, hi, lo);       ahp[96]  = hi; alp[96]  = lo;
    bf16_split2(sdx, sdy, hi, lo);       ahp[128] = hi; alp[128] = lo;
    if (lane == 0) { sAB[nl] = ldv / avg; sAB[8 + nl] = avg / ldv; }
  }
  __syncthreads();

  // ---- phase C: MFMA post-matmul. Wave w -> (tower = w>>1, ntile = w&1).
  // A: [16 x 320] (rows = node&7 dup), B: [320 x 16] cols of this quadrant.
  // g1 over k 0..319 (h+agg); g2/g3 over k 64..319 (agg scaled groups).
  f32x4 acc1 = {0.f, 0.f, 0.f, 0.f};
  f32x4 acc2 = {0.f, 0.f, 0.f, 0.f};
  f32x4 acc3 = {0.f, 0.f, 0.f, 0.f};
  int tw = w >> 1, ntile = w & 1;
  int kq = lane >> 4;
  {
    const bf16x8* Ah = (const bf16x8*)sAhi + (tw * 8 + (lane & 7)) * 42 + kq;
    const bf16x8* Al = (const bf16x8*)sAlo + (tw * 8 + (lane & 7)) * 42 + kq;
    int brow = (tw * 32 + ntile * 16 + (lane & 15)) * 104 + kq;
    const bf16x8* Bh = (const bf16x8*)WBhi + brow;
    const bf16x8* Bl = (const bf16x8*)WBlo + brow;
#pragma unroll
    for (int s = 0; s < 10; s++) {
      bf16x8 ah = Ah[s * 4], al = Al[s * 4];
      bf16x8 b1h = Bh[s * 4], b1l = Bl[s * 4];
      MFMA(acc1, ah, b1h); MFMA(acc1, al, b1h); MFMA(acc1, ah, b1l);
      if (s >= 2) {
        bf16x8 b2h = Bh[40 + (s - 2) * 4], b2l = Bl[40 + (s - 2) * 4];
        bf16x8 b3h = Bh[72 + (s - 2) * 4], b3l = Bl[72 + (s - 2) * 4];
        MFMA(acc2, ah, b2h); MFMA(acc2, al, b2h); MFMA(acc2, ah, b2l);
        MFMA(acc3, ah, b3h); MFMA(acc3, al, b3h); MFMA(acc3, ah, b3l);
      }
    }
  }
  __syncthreads();   // all A-frag LDS reads done -> safe to alias po over sAhi

  // ---- combine groups with per-node scalars; write po[node][64]
  float* spo = (float*)sAhi;   // 512 floats, aliases sAhi
  if (lane < 32) {             // C rows 0..7 = real nodes (8..15 duplicates)
    int colg = tw * 32 + ntile * 16 + (lane & 15);
    float pbv = postb[colg];
    int rbase = kq * 4;
#pragma unroll
    for (int r = 0; r < 4; r++) {
      int nr = rbase + r;
      spo[nr * 64 + colg] = acc1[r] + sAB[nr] * acc2[r] + sAB[8 + nr] * acc3[r] + pbv;
    }
  }
  __syncthreads();

  // ---- lin epilogue: wave w -> nodes w*2, w*2+1; col = lane
  {
    float la0 = linb[lane], la1 = la0;
    const float4* lw4 = (const float4*)linWT + lane;
    const float* p0 = &spo[(w * 2) * 64];
    const float* p1 = p0 + 64;
#pragma unroll
    for (int c4 = 0; c4 < 16; c4++) {
      float4 lwv = lw4[c4 * 64];
      float4 pa = *(const float4*)&p0[c4 * 4];
      float4 pb2 = *(const float4*)&p1[c4 * 4];
      la0 = fmaf(pa.w, lwv.w, fmaf(pa.z, lwv.z, fmaf(pa.y, lwv.y, fmaf(pa.x, lwv.x, la0))));
      la1 = fmaf(pb2.w, lwv.w, fmaf(pb2.z, lwv.z, fmaf(pb2.y, lwv.y, fmaf(pb2.x, lwv.x, la1))));
    }
    size_t ob = (size_t)(n0 + w * 2) * 64 + lane;
    out[ob] = la0;
    out[ob + 64] = la1;
  }
}

// ------------------------------------------------------------------ BN stats
__global__ __launch_bounds__(256) void k_bnstats(const float* __restrict__ y,
                                                 float* __restrict__ bnsum,
                                                 float* __restrict__ bnsumsq) {
  __shared__ float r1[256], r2[256];
  int c = threadIdx.x & 63, r = threadIdx.x >> 6;
  float s = 0, q = 0;
  for (int n = blockIdx.x * 4 + r; n < N_NODES; n += gridDim.x * 4) {
    float v = y[(size_t)n * 64 + c];
    s += v; q = fmaf(v, v, q);
  }
  r1[threadIdx.x] = s; r2[threadIdx.x] = q; __syncthreads();
  if (threadIdx.x < 64) {
    s = r1[threadIdx.x] + r1[threadIdx.x + 64] + r1[threadIdx.x + 128] + r1[threadIdx.x + 192];
    q = r2[threadIdx.x] + r2[threadIdx.x + 64] + r2[threadIdx.x + 128] + r2[threadIdx.x + 192];
    atomicAdd(&bnsum[threadIdx.x], s);
    atomicAdd(&bnsumsq[threadIdx.x], q);
  }
}

// ================================================================== launcher
extern "C" void kernel_launch(void* const* d_in, const int* in_sizes, int n_in,
                              void* d_out, int out_size, void* d_ws, size_t ws_size,
                              hipStream_t stream) {
  const float* x      = (const float*)d_in[0];
  const float* embW   = (const float*)d_in[1];
  const float* embB   = (const float*)d_in[2];
  const float* preW1  = (const float*)d_in[3];
  const float* preb1  = (const float*)d_in[4];
  const float* postW1 = (const float*)d_in[5];
  const float* postb1 = (const float*)d_in[6];
  const float* linW1  = (const float*)d_in[7];
  const float* linb1  = (const float*)d_in[8];
  const float* gamma  = (const float*)d_in[9];
  const float* beta   = (const float*)d_in[10];
  const float* preW2  = (const float*)d_in[11];
  const float* preb2  = (const float*)d_in[12];
  const float* postW2 = (const float*)d_in[13];
  const float* postb2 = (const float*)d_in[14];
  const float* linW2  = (const float*)d_in[15];
  const float* linb2  = (const float*)d_in[16];
  const int*   src    = (const int*)d_in[17];
  const int*   dst    = (const int*)d_in[18];
  float* out = (float*)d_out;

  char* w = (char*)d_ws;
  size_t o = 0;
  int*   deg     = (int*)(w + o);   o += (size_t)N_NODES * 4;
  float* scalars = (float*)(w + o); o += 64;
  float* bnsum   = (float*)(w + o); o += 256;
  float* bnsumsq = (float*)(w + o); o += 256;
  size_t zero_len = o;
  o = (o + 255) & ~(size_t)255;
  int* partials = (int*)(w + o);  o += 256;
  int* row_ptr  = (int*)(w + o);  o += (size_t)(N_NODES + 1) * 4; o = (o + 255) & ~(size_t)255;
  int* cursor   = (int*)(w + o);  o += (size_t)N_NODES * 4;       o = (o + 255) & ~(size_t)255;
  int* csr      = (int*)(w + o);  o += (size_t)E_EDGES * 4;       o = (o + 255) & ~(size_t)255;
  unsigned short* WBhi = (unsigned short*)(w + o); o += (size_t)2 * 53248 * 2;
  unsigned short* WBlo = (unsigned short*)(w + o); o += (size_t)2 * 53248 * 2;
  float* linWT  = (float*)(w + o); o += (size_t)2 * 4096 * 4;
  float* h1 = (float*)(w + o); o += (size_t)N_NODES * 64 * 4;
  float* y1 = (float*)(w + o); o += (size_t)N_NODES * 64 * 4;
  float* h2 = (float*)(w + o); o += (size_t)N_NODES * 64 * 4;
  float* hA = (float*)(w + o); o += (size_t)N_NODES * 128 * 4;
  float* hB = (float*)(w + o); o += (size_t)N_NODES * 128 * 4;

  hipMemsetAsync(w, 0, zero_len, stream);

  // hist + embed (fused, independent)
  k_hist_embed<<<HIST_BLK + EMB_BLK, 256, 0, stream>>>(dst, deg, x, embW, embB, h1);
  // scan phase 1 + log-sum + weight split/transpose (fused, independent)
  k_scanpart_trans<<<SCAN_BLK + TRANS_BLK, 256, 0, stream>>>(
      deg, partials, scalars, postW1, postW2, linW1, linW2, WBhi, WBlo, linWT);
  k_scan_final<<<SCAN_BLK, 256, 0, stream>>>(deg, partials, row_ptr, cursor, scalars);
  k_scatter<<<(E_EDGES + 255) / 256, 256, 0, stream>>>(src, dst, cursor, csr);

  // ----- layer 1
  k_preab<false><<<768, 256, 0, stream>>>(h1, preW1, preb1, nullptr, nullptr,
                                          nullptr, nullptr, nullptr, hA, hB);
  k_conv<<<N_NODES / 8, 256, 0, stream>>>(hA, hB, h1, row_ptr, csr,
                                          WBhi, WBlo, postb1, linWT, linb1, scalars, y1);
  k_bnstats<<<256, 256, 0, stream>>>(y1, bnsum, bnsumsq);
  // ----- layer 2 (BN finalize + relu fused into preab staging)
  k_preab<true><<<768, 256, 0, stream>>>(y1, preW2, preb2, bnsum, bnsumsq,
                                         gamma, beta, h2, hA, hB);
  k_conv<<<N_NODES / 8, 256, 0, stream>>>(hA, hB, h2, row_ptr, csr,
                                          WBhi + 53248, WBlo + 53248, postb2,
                                          linWT + 4096, linb2, scalars, out);
}

// Round 2
// 557.595 us; speedup vs baseline: 1.2449x; 1.2449x over previous
//
#include <hip/hip_runtime.h>
#include <hip/hip_fp16.h>

#define N_NODES 50000
#define E_EDGES 800000
#define IN_F    128
#define H_F     64
#define STD_EPS 1e-5f
#define BN_EPS  1e-5f

#define HIST_BLK 3125   // E_EDGES / 256 exactly
#define EMB_BLK  768
#define SCAN_BLK 49
#define TRANS_BLK 448   // 114688 / 256

typedef __attribute__((ext_vector_type(8))) short bf16x8;
typedef __attribute__((ext_vector_type(4))) float f32x4;

// float -> bf16 bits (round-to-nearest-even), in low 16 bits
__device__ __forceinline__ unsigned bf16_rne(float f) {
  unsigned u = __float_as_uint(f);
  return (u + 0x7fffu + ((u >> 16) & 1u)) >> 16;
}
// split (x,y) into packed bf16x2 hi and bf16x2 lo (residual)
__device__ __forceinline__ void bf16_split2(float x, float y, unsigned& hi, unsigned& lo) {
  unsigned hx = bf16_rne(x), hy = bf16_rne(y);
  float rx = x - __uint_as_float(hx << 16);
  float ry = y - __uint_as_float(hy << 16);
  hi = hx | (hy << 16);
  lo = bf16_rne(rx) | (bf16_rne(ry) << 16);
}

#define MFMA(acc, a, b) acc = __builtin_amdgcn_mfma_f32_16x16x32_bf16(a, b, acc, 0, 0, 0)

// ------------------------------------------- fused degree hist + embed GEMM
__global__ __launch_bounds__(256) void k_hist_embed(const int* __restrict__ dst,
                                                    int* __restrict__ deg,
                                                    const float* __restrict__ x,
                                                    const float* __restrict__ W,
                                                    const float* __restrict__ bias,
                                                    float* __restrict__ h) {
  __shared__ float sW[IN_F * 64];    // 32 KB
  __shared__ float sx[IN_F * 36];    // x_T[k][32+pad4] 18 KB
  if (blockIdx.x < HIST_BLK) {
    int e = blockIdx.x * 256 + threadIdx.x;
    atomicAdd(&deg[dst[e]], 1);      // grid sized so e < E_EDGES always
    return;
  }
  for (int i = threadIdx.x; i < IN_F * 64; i += 256) sW[i] = W[i];
  int f = threadIdx.x & 63, ng = threadIdx.x >> 6;
  float bj = bias[f];
  const int NGRP = (N_NODES + 31) / 32;   // 1563
  for (int grp = blockIdx.x - HIST_BLK; grp < NGRP; grp += EMB_BLK) {
    int n0 = grp * 32;
    __syncthreads();
    for (int idx = threadIdx.x; idx < 32 * IN_F; idx += 256) {
      int nl = idx >> 7, k = idx & 127;
      int n = n0 + nl;
      sx[k * 36 + nl] = (n < N_NODES) ? x[(size_t)n * IN_F + k] : 0.f;
    }
    __syncthreads();
    float a[8] = {bj, bj, bj, bj, bj, bj, bj, bj};
    const float* xp = &sx[ng * 8];
#pragma unroll 4
    for (int k = 0; k < IN_F; k++) {
      float4 h0 = *(const float4*)&xp[k * 36];
      float4 h1 = *(const float4*)&xp[k * 36 + 4];
      float w = sW[k * 64 + f];
      a[0] = fmaf(h0.x, w, a[0]); a[1] = fmaf(h0.y, w, a[1]);
      a[2] = fmaf(h0.z, w, a[2]); a[3] = fmaf(h0.w, w, a[3]);
      a[4] = fmaf(h1.x, w, a[4]); a[5] = fmaf(h1.y, w, a[5]);
      a[6] = fmaf(h1.z, w, a[6]); a[7] = fmaf(h1.w, w, a[7]);
    }
#pragma unroll
    for (int j = 0; j < 8; j++) {
      int n = n0 + ng * 8 + j;
      if (n < N_NODES) h[(size_t)n * 64 + f] = a[j];
    }
  }
}

// --------------------- fused scan phase-1 (+ sum log(deg+1)) and transpose
// Weight prep emits bf16 hi/lo split, transposed to [layer][t][col][f=832]
// (k-contiguous per output column -> MFMA B-fragment layout).
__global__ __launch_bounds__(256) void k_scanpart_trans(const int* __restrict__ deg,
                                                        int* __restrict__ partials,
                                                        float* __restrict__ scalars,
                                                        const float* __restrict__ pW1,
                                                        const float* __restrict__ pW2,
                                                        const float* __restrict__ lW1,
                                                        const float* __restrict__ lW2,
                                                        unsigned short* __restrict__ WBhi,
                                                        unsigned short* __restrict__ WBlo,
                                                        float* __restrict__ lWT) {
  __shared__ int red[256];
  __shared__ float redf[256];
  if (blockIdx.x < SCAN_BLK) {
    int base = blockIdx.x * 1024;
    int s = 0; float ls = 0.f;
    for (int j = threadIdx.x; j < 1024; j += 256) {
      int i = base + j;
      if (i < N_NODES) { int d = deg[i]; s += d; ls += logf((float)d + 1.0f); }
    }
    red[threadIdx.x] = s; redf[threadIdx.x] = ls; __syncthreads();
    for (int st = 128; st > 0; st >>= 1) {
      if (threadIdx.x < st) {
        red[threadIdx.x] += red[threadIdx.x + st];
        redf[threadIdx.x] += redf[threadIdx.x + st];
      }
      __syncthreads();
    }
    if (threadIdx.x == 0) {
      partials[blockIdx.x] = red[0];
      atomicAdd(&scalars[0], redf[0]);
    }
    return;
  }
  int idx = (blockIdx.x - SCAN_BLK) * 256 + threadIdx.x;
  if (idx < 106496) {
    // idx = ((layer*2 + t)*32 + col)*832 + f
    int f = idx % 832;
    int rest = idx / 832;            // 0..127
    int col = rest & 31, tt = rest >> 5;   // tt = layer*2 + t
    const float* srcp = (tt >= 2) ? pW2 : pW1;
    float v = srcp[((size_t)(tt & 1) * 832 + f) * 32 + col];
    unsigned hb = bf16_rne(v);
    float rsd = v - __uint_as_float(hb << 16);
    WBhi[idx] = (unsigned short)hb;
    WBlo[idx] = (unsigned short)bf16_rne(rsd);
  } else if (idx < 114688) {
    int jj = idx - 106496;
    int layer = jj / 4096, r2 = jj % 4096;
    int c4 = r2 / 256, r3 = r2 % 256;
    int col = r3 / 4, j = r3 % 4;
    const float* srcl = layer ? lW2 : lW1;
    lWT[jj] = srcl[(c4 * 4 + j) * 64 + col];
  }
}

// ----------------------- scan final (self-computed prefix, no mid kernel)
__global__ __launch_bounds__(256) void k_scan_final(const int* __restrict__ deg,
                                                    const int* __restrict__ partials,
                                                    int* __restrict__ row_ptr,
                                                    int* __restrict__ cursor,
                                                    float* __restrict__ scalars) {
  __shared__ int ts[256];
  __shared__ int sbase;
  if (threadIdx.x == 0) {
    int pre = 0;
    for (int b = 0; b < (int)blockIdx.x; b++) pre += partials[b];
    sbase = pre;
    if (blockIdx.x == 0) {
      scalars[1] = scalars[0] / (float)N_NODES;   // avg_log
      row_ptr[N_NODES] = E_EDGES;
    }
  }
  int base = blockIdx.x * 1024 + threadIdx.x * 4;
  int d[4]; int s = 0;
#pragma unroll
  for (int j = 0; j < 4; j++) {
    int i = base + j;
    d[j] = (i < N_NODES) ? deg[i] : 0;
    s += d[j];
  }
  ts[threadIdx.x] = s; __syncthreads();
  for (int off = 1; off < 256; off <<= 1) {
    int t = (threadIdx.x >= off) ? ts[threadIdx.x - off] : 0;
    __syncthreads();
    ts[threadIdx.x] += t;
    __syncthreads();
  }
  int excl = (threadIdx.x > 0) ? ts[threadIdx.x - 1] : 0;
  int run = sbase + excl;
#pragma unroll
  for (int j = 0; j < 4; j++) {
    int i = base + j;
    if (i < N_NODES) { row_ptr[i] = run; cursor[i] = run; run += d[j]; }
  }
}

// ------------------------------------------------------------------- scatter
__global__ __launch_bounds__(256) void k_scatter(const int* __restrict__ src,
                                                 const int* __restrict__ dst,
                                                 int* __restrict__ cursor,
                                                 int* __restrict__ csr_src) {
  int e = blockIdx.x * 256 + threadIdx.x;
  if (e < E_EDGES) {
    int d = dst[e];
    int p = atomicAdd(&cursor[d], 1);
    csr_src[p] = src[e];
  }
}

// ------------------------------------------------------------------ pre A/B
// hB now stored fp16 (halves gather traffic in k_conv; rel err 2^-11).
template <bool BN>
__global__ __launch_bounds__(256) void k_preab(const float* __restrict__ hin,
                                               const float* __restrict__ preW,
                                               const float* __restrict__ preb,
                                               const float* __restrict__ bnsum,
                                               const float* __restrict__ bnsumsq,
                                               const float* __restrict__ gamma,
                                               const float* __restrict__ beta,
                                               float* __restrict__ h2out,
                                               float* __restrict__ hA,
                                               __half* __restrict__ hB) {
  __shared__ float sWp[64 * 128];   // 32 KB packed [k][f][{A,B}]
  __shared__ float sh[64 * 68];     // h_T[k][64+pad4]  17408 B
  __shared__ float sbn[128];        // scale[64], shift[64]
  int t = blockIdx.x & 1;
  const float* Wsrc = preW + (size_t)t * 128 * 64;
  for (int i = threadIdx.x; i < 64 * 64; i += 256) {
    int k = i >> 6, f = i & 63;
    float wa = Wsrc[k * 64 + f];
    float wb = Wsrc[(64 + k) * 64 + f];
    *(float2*)&sWp[k * 128 + f * 2] = make_float2(wa, wb);
  }
  if (BN && threadIdx.x < 64) {
    int c = threadIdx.x;
    float mu = bnsum[c] * (1.f / N_NODES);
    float var = bnsumsq[c] * (1.f / N_NODES) - mu * mu;
    float sc = gamma[c] / sqrtf(var + BN_EPS);
    sbn[c] = sc;
    sbn[64 + c] = fmaf(-mu, sc, beta[c]);
  }
  int f = threadIdx.x & 63, ng = threadIdx.x >> 6;   // ng 0..3 -> 16 nodes each
  float pb = preb[t * 64 + f];
  int nblk2 = gridDim.x >> 1;
  const int NGRP = (N_NODES + 63) / 64;   // 782
  for (int grp = blockIdx.x >> 1; grp < NGRP; grp += nblk2) {
    int n0 = grp * 64;
    __syncthreads();
    for (int idx = threadIdx.x; idx < 64 * 64; idx += 256) {
      int nl = idx >> 6, k = idx & 63;
      int n = n0 + nl;
      float v = 0.f;
      if (n < N_NODES) {
        v = hin[(size_t)n * 64 + k];
        if (BN) {
          v = fmaxf(fmaf(v, sbn[k], sbn[64 + k]), 0.f);
          if (t == 0) h2out[(size_t)n * 64 + k] = v;
        }
      }
      sh[k * 68 + nl] = v;
    }
    __syncthreads();
    float a[16], b[16];
#pragma unroll
    for (int j = 0; j < 16; j++) { a[j] = pb; b[j] = 0.f; }
    const float* hp = &sh[ng * 16];
    const float* wp = &sWp[f * 2];
#pragma unroll 2
    for (int k = 0; k < 64; k++) {
      float4 h0 = *(const float4*)&hp[k * 68];
      float4 h1 = *(const float4*)&hp[k * 68 + 4];
      float4 h2 = *(const float4*)&hp[k * 68 + 8];
      float4 h3 = *(const float4*)&hp[k * 68 + 12];
      float2 w2 = *(const float2*)&wp[k * 128];
      a[0]  = fmaf(h0.x, w2.x, a[0]);  b[0]  = fmaf(h0.x, w2.y, b[0]);
      a[1]  = fmaf(h0.y, w2.x, a[1]);  b[1]  = fmaf(h0.y, w2.y, b[1]);
      a[2]  = fmaf(h0.z, w2.x, a[2]);  b[2]  = fmaf(h0.z, w2.y, b[2]);
      a[3]  = fmaf(h0.w, w2.x, a[3]);  b[3]  = fmaf(h0.w, w2.y, b[3]);
      a[4]  = fmaf(h1.x, w2.x, a[4]);  b[4]  = fmaf(h1.x, w2.y, b[4]);
      a[5]  = fmaf(h1.y, w2.x, a[5]);  b[5]  = fmaf(h1.y, w2.y, b[5]);
      a[6]  = fmaf(h1.z, w2.x, a[6]);  b[6]  = fmaf(h1.z, w2.y, b[6]);
      a[7]  = fmaf(h1.w, w2.x, a[7]);  b[7]  = fmaf(h1.w, w2.y, b[7]);
      a[8]  = fmaf(h2.x, w2.x, a[8]);  b[8]  = fmaf(h2.x, w2.y, b[8]);
      a[9]  = fmaf(h2.y, w2.x, a[9]);  b[9]  = fmaf(h2.y, w2.y, b[9]);
      a[10] = fmaf(h2.z, w2.x, a[10]); b[10] = fmaf(h2.z, w2.y, b[10]);
      a[11] = fmaf(h2.w, w2.x, a[11]); b[11] = fmaf(h2.w, w2.y, b[11]);
      a[12] = fmaf(h3.x, w2.x, a[12]); b[12] = fmaf(h3.x, w2.y, b[12]);
      a[13] = fmaf(h3.y, w2.x, a[13]); b[13] = fmaf(h3.y, w2.y, b[13]);
      a[14] = fmaf(h3.z, w2.x, a[14]); b[14] = fmaf(h3.z, w2.y, b[14]);
      a[15] = fmaf(h3.w, w2.x, a[15]); b[15] = fmaf(h3.w, w2.y, b[15]);
    }
    int tf = t * 64 + f;
#pragma unroll
    for (int j = 0; j < 16; j++) {
      int n = n0 + ng * 16 + j;
      if (n < N_NODES) {
        hA[(size_t)n * 128 + tf] = a[j];
        hB[(size_t)n * 128 + tf] = __float2half(b[j]);
      }
    }
  }
}

// --------------------------------------------------- fused conv main kernel
// 8 nodes/block. Phase A: fp16 hB gather, 8-deep double-buffered, no per-edge
// +a (aggregation is shift-invariant; shift applied in epilogue).
// Phase C: MFMA with rotating 2-ahead B prefetch; 36 B loads (b2/b3 lo dropped).
__global__ __launch_bounds__(256, 6) void k_conv(const float* __restrict__ hA,
                                                 const __half* __restrict__ hB,
                                                 const float* __restrict__ hskip,
                                                 const int* __restrict__ row_ptr,
                                                 const int* __restrict__ csr_src,
                                                 const unsigned short* __restrict__ WBhi,
                                                 const unsigned short* __restrict__ WBlo,
                                                 const float* __restrict__ postb,
                                                 const float* __restrict__ linWT,
                                                 const float* __restrict__ linb,
                                                 const float* __restrict__ scalars,
                                                 float* __restrict__ out) {
  __shared__ unsigned sAhi[2688];   // [t][node8][168 u32] = 10752 B
  __shared__ unsigned sAlo[2688];   // 10752 B  (total 21568 B -> 7 blk/CU max)
  __shared__ float sAB[16];         // sA[0..7], sB[8..15]
  int w = threadIdx.x >> 6, lane = threadIdx.x & 63;
  int n0 = blockIdx.x * 8;
  int t = lane >> 5, fb2 = (lane & 31) * 2;
  int off = t * 64 + fb2;
  float avg = scalars[1];

  // ---- phase A: aggregation, 2 nodes per wave, 8 loads in flight, dbuf
#pragma unroll 1
  for (int k = 0; k < 2; k++) {
    int nl = w * 2 + k;
    int n = n0 + nl;
    float2 a = *(const float2*)&hA[(size_t)n * 128 + off];
    int rp0 = __builtin_amdgcn_readfirstlane(row_ptr[n]);
    int rp1 = __builtin_amdgcn_readfirstlane(row_ptr[n + 1]);
    int dg = rp1 - rp0;
    float sx0=0,sy0=0,qx0=0,qy0=0, sx1=0,sy1=0,qx1=0,qy1=0;
    float mnx0=INFINITY,mny0=INFINITY,mxx0=-INFINITY,mxy0=-INFINITY;
    float mnx1=INFINITY,mny1=INFINITY,mxx1=-INFINITY,mxy1=-INFINITY;
    int nloop = dg >> 3;
    if (nloop > 0) {
      int b = rp0;
      int s0=csr_src[b],s1=csr_src[b+1],s2=csr_src[b+2],s3=csr_src[b+3],
          s4=csr_src[b+4],s5=csr_src[b+5],s6=csr_src[b+6],s7=csr_src[b+7];
      __half2 qa0 = *(const __half2*)&hB[(size_t)s0 * 128 + off];
      __half2 qa1 = *(const __half2*)&hB[(size_t)s1 * 128 + off];
      __half2 qa2 = *(const __half2*)&hB[(size_t)s2 * 128 + off];
      __half2 qa3 = *(const __half2*)&hB[(size_t)s3 * 128 + off];
      __half2 qa4 = *(const __half2*)&hB[(size_t)s4 * 128 + off];
      __half2 qa5 = *(const __half2*)&hB[(size_t)s5 * 128 + off];
      __half2 qa6 = *(const __half2*)&hB[(size_t)s6 * 128 + off];
      __half2 qa7 = *(const __half2*)&hB[(size_t)s7 * 128 + off];
      for (int it = 0; ; it++) {
        bool more = (it + 1 < nloop);
        __half2 qb0, qb1, qb2, qb3, qb4, qb5, qb6, qb7;
        if (more) {
          int c = rp0 + ((it + 1) << 3);
          s0=csr_src[c];s1=csr_src[c+1];s2=csr_src[c+2];s3=csr_src[c+3];
          s4=csr_src[c+4];s5=csr_src[c+5];s6=csr_src[c+6];s7=csr_src[c+7];
          qb0 = *(const __half2*)&hB[(size_t)s0 * 128 + off];
          qb1 = *(const __half2*)&hB[(size_t)s1 * 128 + off];
          qb2 = *(const __half2*)&hB[(size_t)s2 * 128 + off];
          qb3 = *(const __half2*)&hB[(size_t)s3 * 128 + off];
          qb4 = *(const __half2*)&hB[(size_t)s4 * 128 + off];
          qb5 = *(const __half2*)&hB[(size_t)s5 * 128 + off];
          qb6 = *(const __half2*)&hB[(size_t)s6 * 128 + off];
          qb7 = *(const __half2*)&hB[(size_t)s7 * 128 + off];
        }
        float2 v0 = __half22float2(qa0), v1 = __half22float2(qa1);
        float2 v2 = __half22float2(qa2), v3 = __half22float2(qa3);
        float2 v4 = __half22float2(qa4), v5 = __half22float2(qa5);
        float2 v6 = __half22float2(qa6), v7 = __half22float2(qa7);
        sx0 += v0.x; qx0 = fmaf(v0.x,v0.x,qx0); mnx0 = fminf(mnx0,v0.x); mxx0 = fmaxf(mxx0,v0.x);
        sy0 += v0.y; qy0 = fmaf(v0.y,v0.y,qy0); mny0 = fminf(mny0,v0.y); mxy0 = fmaxf(mxy0,v0.y);
        sx1 += v1.x; qx1 = fmaf(v1.x,v1.x,qx1); mnx1 = fminf(mnx1,v1.x); mxx1 = fmaxf(mxx1,v1.x);
        sy1 += v1.y; qy1 = fmaf(v1.y,v1.y,qy1); mny1 = fminf(mny1,v1.y); mxy1 = fmaxf(mxy1,v1.y);
        sx0 += v2.x; qx0 = fmaf(v2.x,v2.x,qx0); mnx0 = fminf(mnx0,v2.x); mxx0 = fmaxf(mxx0,v2.x);
        sy0 += v2.y; qy0 = fmaf(v2.y,v2.y,qy0); mny0 = fminf(mny0,v2.y); mxy0 = fmaxf(mxy0,v2.y);
        sx1 += v3.x; qx1 = fmaf(v3.x,v3.x,qx1); mnx1 = fminf(mnx1,v3.x); mxx1 = fmaxf(mxx1,v3.x);
        sy1 += v3.y; qy1 = fmaf(v3.y,v3.y,qy1); mny1 = fminf(mny1,v3.y); mxy1 = fmaxf(mxy1,v3.y);
        sx0 += v4.x; qx0 = fmaf(v4.x,v4.x,qx0); mnx0 = fminf(mnx0,v4.x); mxx0 = fmaxf(mxx0,v4.x);
        sy0 += v4.y; qy0 = fmaf(v4.y,v4.y,qy0); mny0 = fminf(mny0,v4.y); mxy0 = fmaxf(mxy0,v4.y);
        sx1 += v5.x; qx1 = fmaf(v5.x,v5.x,qx1); mnx1 = fminf(mnx1,v5.x); mxx1 = fmaxf(mxx1,v5.x);
        sy1 += v5.y; qy1 = fmaf(v5.y,v5.y,qy1); mny1 = fminf(mny1,v5.y); mxy1 = fmaxf(mxy1,v5.y);
        sx0 += v6.x; qx0 = fmaf(v6.x,v6.x,qx0); mnx0 = fminf(mnx0,v6.x); mxx0 = fmaxf(mxx0,v6.x);
        sy0 += v6.y; qy0 = fmaf(v6.y,v6.y,qy0); mny0 = fminf(mny0,v6.y); mxy0 = fmaxf(mxy0,v6.y);
        sx1 += v7.x; qx1 = fmaf(v7.x,v7.x,qx1); mnx1 = fminf(mnx1,v7.x); mxx1 = fmaxf(mxx1,v7.x);
        sy1 += v7.y; qy1 = fmaf(v7.y,v7.y,qy1); mny1 = fminf(mny1,v7.y); mxy1 = fmaxf(mxy1,v7.y);
        if (!more) break;
        qa0=qb0; qa1=qb1; qa2=qb2; qa3=qb3; qa4=qb4; qa5=qb5; qa6=qb6; qa7=qb7;
      }
    }
    {   // masked tail: 0..7 edges, all loads issued together (r wave-uniform)
      int i = rp0 + (nloop << 3);
      int r = rp1 - i;
      if (r > 0) {
        int sj[7];
#pragma unroll
        for (int j = 0; j < 7; j++) sj[j] = csr_src[i + (j < r ? j : r - 1)];
        __half2 hq[7];
#pragma unroll
        for (int j = 0; j < 7; j++) hq[j] = *(const __half2*)&hB[(size_t)sj[j] * 128 + off];
#pragma unroll
        for (int j = 0; j < 7; j++) {
          if (j < r) {
            float2 v = __half22float2(hq[j]);
            if (j & 1) {
              sx1 += v.x; qx1 = fmaf(v.x,v.x,qx1); mnx1 = fminf(mnx1,v.x); mxx1 = fmaxf(mxx1,v.x);
              sy1 += v.y; qy1 = fmaf(v.y,v.y,qy1); mny1 = fminf(mny1,v.y); mxy1 = fmaxf(mxy1,v.y);
            } else {
              sx0 += v.x; qx0 = fmaf(v.x,v.x,qx0); mnx0 = fminf(mnx0,v.x); mxx0 = fmaxf(mxx0,v.x);
              sy0 += v.y; qy0 = fmaf(v.y,v.y,qy0); mny0 = fminf(mny0,v.y); mxy0 = fmaxf(mxy0,v.y);
            }
          }
        }
      }
    }
    float cnt = (float)(dg > 0 ? dg : 1);
    float inv = 1.0f / cnt;
    float mrx = (sx0 + sx1) * inv, mry = (sy0 + sy1) * inv;
    float sdx = sqrtf(fmaxf((qx0 + qx1) * inv - mrx * mrx, 0.f) + STD_EPS);
    float sdy = sqrtf(fmaxf((qy0 + qy1) * inv - mry * mry, 0.f) + STD_EPS);
    float mnx = fminf(mnx0, mnx1), mny = fminf(mny0, mny1);
    float mxx = fmaxf(mxx0, mxx1), mxy = fmaxf(mxy0, mxy1);
    float ax = a.x, ay = a.y;
    if (dg == 0) { mnx = 0; mny = 0; mxx = 0; mxy = 0; ax = 0; ay = 0; }
    float meanx = mrx + ax, meany = mry + ay;
    mnx += ax; mny += ay; mxx += ax; mxy += ay;
    float ldv = logf(cnt + 1.f);
    float2 hsv = *(const float2*)&hskip[(size_t)n * 64 + fb2];
    // write 5 slices as bf16 hi/lo into A rows (k-contiguous, 672B stride)
    unsigned* ahp = &sAhi[(t * 8 + nl) * 168 + (fb2 >> 1)];
    unsigned* alp = &sAlo[(t * 8 + nl) * 168 + (fb2 >> 1)];
    unsigned hi, lo;
    bf16_split2(hsv.x, hsv.y, hi, lo);   ahp[0]   = hi; alp[0]   = lo;
    bf16_split2(meanx, meany, hi, lo);   ahp[32]  = hi; alp[32]  = lo;
    bf16_split2(mnx, mny, hi, lo);       ahp[64]  = hi; alp[64]  = lo;
    bf16_split2(mxx, mxy, hi, lo);       ahp[96]  = hi; alp[96]  = lo;
    bf16_split2(sdx, sdy, hi, lo);       ahp[128] = hi; alp[128] = lo;
    if (lane == 0) { sAB[nl] = ldv / avg; sAB[8 + nl] = avg / ldv; }
  }
  __syncthreads();

  // ---- phase C: MFMA post-matmul. Wave w -> (tower = w>>1, ntile = w&1).
  f32x4 acc1 = {0.f, 0.f, 0.f, 0.f};
  f32x4 acc2 = {0.f, 0.f, 0.f, 0.f};
  f32x4 acc3 = {0.f, 0.f, 0.f, 0.f};
  int tw = w >> 1, ntile = w & 1;
  int kq = lane >> 4;
  {
    const bf16x8* Ah = (const bf16x8*)sAhi + (tw * 8 + (lane & 7)) * 42 + kq;
    const bf16x8* Al = (const bf16x8*)sAlo + (tw * 8 + (lane & 7)) * 42 + kq;
    int brow = (tw * 32 + ntile * 16 + (lane & 15)) * 104 + kq;
    const bf16x8* Bh = (const bf16x8*)WBhi + brow;
    const bf16x8* Bl = (const bf16x8*)WBlo + brow;
    // g1: k 0..319, 3-product split precision; rotating 2-ahead prefetch
    bf16x8 bh_0 = Bh[0], bl_0 = Bl[0];
    bf16x8 bh_1 = Bh[4], bl_1 = Bl[4];
#pragma unroll
    for (int s = 0; s < 10; s++) {
      bf16x8 bh_n, bl_n;
      if (s < 8) { bh_n = Bh[(s + 2) * 4]; bl_n = Bl[(s + 2) * 4]; }
      bf16x8 ah = Ah[s * 4], al = Al[s * 4];
      MFMA(acc1, ah, bh_0); MFMA(acc1, al, bh_0); MFMA(acc1, ah, bl_0);
      bh_0 = bh_1; bl_0 = bl_1; bh_1 = bh_n; bl_1 = bl_n;
    }
    // g2/g3: k 64..319 scaled-agg groups; B hi-only (lo loads dropped)
    bf16x8 c_0 = Bh[40], d_0 = Bh[72];
    bf16x8 c_1 = Bh[44], d_1 = Bh[76];
#pragma unroll
    for (int s = 0; s < 8; s++) {
      bf16x8 c_n, d_n;
      if (s < 6) { c_n = Bh[48 + s * 4]; d_n = Bh[80 + s * 4]; }
      bf16x8 ah = Ah[(s + 2) * 4], al = Al[(s + 2) * 4];
      MFMA(acc2, ah, c_0); MFMA(acc2, al, c_0);
      MFMA(acc3, ah, d_0); MFMA(acc3, al, d_0);
      c_0 = c_1; d_0 = d_1; c_1 = c_n; d_1 = d_n;
    }
  }
  __syncthreads();   // all A-frag LDS reads done -> safe to alias po over sAhi

  // ---- combine groups with per-node scalars; write po[node][64]
  float* spo = (float*)sAhi;   // 512 floats, aliases sAhi
  if (lane < 32) {             // C rows 0..7 = real nodes (8..15 duplicates)
    int colg = tw * 32 + ntile * 16 + (lane & 15);
    float pbv = postb[colg];
    int rbase = kq * 4;
#pragma unroll
    for (int r = 0; r < 4; r++) {
      int nr = rbase + r;
      spo[nr * 64 + colg] = acc1[r] + sAB[nr] * acc2[r] + sAB[8 + nr] * acc3[r] + pbv;
    }
  }
  __syncthreads();

  // ---- lin epilogue: wave w -> nodes w*2, w*2+1; col = lane
  {
    float la0 = linb[lane], la1 = la0;
    const float4* lw4 = (const float4*)linWT + lane;
    const float* p0 = &spo[(w * 2) * 64];
    const float* p1 = p0 + 64;
#pragma unroll
    for (int c4 = 0; c4 < 16; c4++) {
      float4 lwv = lw4[c4 * 64];
      float4 pa = *(const float4*)&p0[c4 * 4];
      float4 pb2 = *(const float4*)&p1[c4 * 4];
      la0 = fmaf(pa.w, lwv.w, fmaf(pa.z, lwv.z, fmaf(pa.y, lwv.y, fmaf(pa.x, lwv.x, la0))));
      la1 = fmaf(pb2.w, lwv.w, fmaf(pb2.z, lwv.z, fmaf(pb2.y, lwv.y, fmaf(pb2.x, lwv.x, la1))));
    }
    size_t ob = (size_t)(n0 + w * 2) * 64 + lane;
    out[ob] = la0;
    out[ob + 64] = la1;
  }
}

// ------------------------------------------------------------------ BN stats
__global__ __launch_bounds__(256) void k_bnstats(const float* __restrict__ y,
                                                 float* __restrict__ bnsum,
                                                 float* __restrict__ bnsumsq) {
  __shared__ float r1[256], r2[256];
  int c = threadIdx.x & 63, r = threadIdx.x >> 6;
  float s = 0, q = 0;
  for (int n = blockIdx.x * 4 + r; n < N_NODES; n += gridDim.x * 4) {
    float v = y[(size_t)n * 64 + c];
    s += v; q = fmaf(v, v, q);
  }
  r1[threadIdx.x] = s; r2[threadIdx.x] = q; __syncthreads();
  if (threadIdx.x < 64) {
    s = r1[threadIdx.x] + r1[threadIdx.x + 64] + r1[threadIdx.x + 128] + r1[threadIdx.x + 192];
    q = r2[threadIdx.x] + r2[threadIdx.x + 64] + r2[threadIdx.x + 128] + r2[threadIdx.x + 192];
    atomicAdd(&bnsum[threadIdx.x], s);
    atomicAdd(&bnsumsq[threadIdx.x], q);
  }
}

// ================================================================== launcher
extern "C" void kernel_launch(void* const* d_in, const int* in_sizes, int n_in,
                              void* d_out, int out_size, void* d_ws, size_t ws_size,
                              hipStream_t stream) {
  const float* x      = (const float*)d_in[0];
  const float* embW   = (const float*)d_in[1];
  const float* embB   = (const float*)d_in[2];
  const float* preW1  = (const float*)d_in[3];
  const float* preb1  = (const float*)d_in[4];
  const float* postW1 = (const float*)d_in[5];
  const float* postb1 = (const float*)d_in[6];
  const float* linW1  = (const float*)d_in[7];
  const float* linb1  = (const float*)d_in[8];
  const float* gamma  = (const float*)d_in[9];
  const float* beta   = (const float*)d_in[10];
  const float* preW2  = (const float*)d_in[11];
  const float* preb2  = (const float*)d_in[12];
  const float* postW2 = (const float*)d_in[13];
  const float* postb2 = (const float*)d_in[14];
  const float* linW2  = (const float*)d_in[15];
  const float* linb2  = (const float*)d_in[16];
  const int*   src    = (const int*)d_in[17];
  const int*   dst    = (const int*)d_in[18];
  float* out = (float*)d_out;

  char* w = (char*)d_ws;
  size_t o = 0;
  int*   deg     = (int*)(w + o);   o += (size_t)N_NODES * 4;
  float* scalars = (float*)(w + o); o += 64;
  float* bnsum   = (float*)(w + o); o += 256;
  float* bnsumsq = (float*)(w + o); o += 256;
  size_t zero_len = o;
  o = (o + 255) & ~(size_t)255;
  int* partials = (int*)(w + o);  o += 256;
  int* row_ptr  = (int*)(w + o);  o += (size_t)(N_NODES + 1) * 4; o = (o + 255) & ~(size_t)255;
  int* cursor   = (int*)(w + o);  o += (size_t)N_NODES * 4;       o = (o + 255) & ~(size_t)255;
  int* csr      = (int*)(w + o);  o += (size_t)E_EDGES * 4;       o = (o + 255) & ~(size_t)255;
  unsigned short* WBhi = (unsigned short*)(w + o); o += (size_t)2 * 53248 * 2;
  unsigned short* WBlo = (unsigned short*)(w + o); o += (size_t)2 * 53248 * 2;
  float* linWT  = (float*)(w + o); o += (size_t)2 * 4096 * 4;
  float* h1 = (float*)(w + o); o += (size_t)N_NODES * 64 * 4;
  float* y1 = (float*)(w + o); o += (size_t)N_NODES * 64 * 4;
  float* h2 = (float*)(w + o); o += (size_t)N_NODES * 64 * 4;
  float* hA = (float*)(w + o); o += (size_t)N_NODES * 128 * 4;
  __half* hBh = (__half*)(w + o); o += (size_t)N_NODES * 128 * 2;

  hipMemsetAsync(w, 0, zero_len, stream);

  // hist + embed (fused, independent)
  k_hist_embed<<<HIST_BLK + EMB_BLK, 256, 0, stream>>>(dst, deg, x, embW, embB, h1);
  // scan phase 1 + log-sum + weight split/transpose (fused, independent)
  k_scanpart_trans<<<SCAN_BLK + TRANS_BLK, 256, 0, stream>>>(
      deg, partials, scalars, postW1, postW2, linW1, linW2, WBhi, WBlo, linWT);
  k_scan_final<<<SCAN_BLK, 256, 0, stream>>>(deg, partials, row_ptr, cursor, scalars);
  k_scatter<<<(E_EDGES + 255) / 256, 256, 0, stream>>>(src, dst, cursor, csr);

  // ----- layer 1
  k_preab<false><<<768, 256, 0, stream>>>(h1, preW1, preb1, nullptr, nullptr,
                                          nullptr, nullptr, nullptr, hA, hBh);
  k_conv<<<N_NODES / 8, 256, 0, stream>>>(hA, hBh, h1, row_ptr, csr,
                                          WBhi, WBlo, postb1, linWT, linb1, scalars, y1);
  k_bnstats<<<256, 256, 0, stream>>>(y1, bnsum, bnsumsq);
  // ----- layer 2 (BN finalize + relu fused into preab staging)
  k_preab<true><<<768, 256, 0, stream>>>(y1, preW2, preb2, bnsum, bnsumsq,
                                         gamma, beta, h2, hA, hBh);
  k_conv<<<N_NODES / 8, 256, 0, stream>>>(hA, hBh, h2, row_ptr, csr,
                                          WBhi + 53248, WBlo + 53248, postb2,
                                          linWT + 4096, linb2, scalars, out);
}